// Round 1
// baseline (883.562 us; speedup 1.0000x reference)
//
#include <hip/hip_runtime.h>
#include <math.h>

// Problem constants (fixed by the reference)
constexpr int   N   = 50000;
constexpr int   E   = 600000;
constexpr int   FIN = 128;
constexpr int   H   = 64;
constexpr int   C   = 40;
constexpr int   K   = 10;
constexpr float CK  = (1.0f - 0.1f) / 10.0f;  // (1-alpha)/K
constexpr float AL  = 0.1f;                   // alpha

// ---------------------------------------------------------------------------
// y0 = x @ W1   (N x 128) @ (128 x 64)
// One wave per node row (lane = output column j). W1 + 4 x-rows staged in LDS.
// ---------------------------------------------------------------------------
__global__ __launch_bounds__(256) void k_gemm1(const float* __restrict__ x,
                                               const float* __restrict__ W1,
                                               float* __restrict__ y0) {
    __shared__ float ws[FIN * H];   // 32 KB
    __shared__ float xs[4 * FIN];   // 2 KB
    for (int t = threadIdx.x; t < FIN * H; t += 256) ws[t] = W1[t];
    int node0 = blockIdx.x * 4;
    for (int t = threadIdx.x; t < 4 * FIN; t += 256) {
        int nl = t >> 7;
        int k  = t & 127;
        int node = node0 + nl;
        xs[t] = (node < N) ? x[node * FIN + k] : 0.0f;
    }
    __syncthreads();
    int nl = threadIdx.x >> 6;
    int j  = threadIdx.x & 63;
    int node = node0 + nl;
    if (node >= N) return;
    float s = 0.0f;
    const float* xr = &xs[nl * FIN];
#pragma unroll 8
    for (int k = 0; k < FIN; ++k) s = fmaf(xr[k], ws[k * H + j], s);
    y0[node * H + j] = s;
}

// ---------------------------------------------------------------------------
// Degree (weighted) + per-row edge count via atomics
// ---------------------------------------------------------------------------
__global__ void k_degcount(const int* __restrict__ row, const float* __restrict__ w,
                           float* __restrict__ deg, int* __restrict__ cnt) {
    int e = blockIdx.x * blockDim.x + threadIdx.x;
    if (e >= E) return;
    int r = row[e];
    atomicAdd(&deg[r], w[e]);
    atomicAdd(&cnt[r], 1);
}

// dinv = rsqrt(deg + 1)  (self-loop weight 1 => deg_total >= 1 always)
__global__ void k_dinv(const float* __restrict__ deg, float* __restrict__ dinv,
                       float* __restrict__ dinv2) {
    int i = blockIdx.x * blockDim.x + threadIdx.x;
    if (i >= N) return;
    float d  = deg[i] + 1.0f;
    float di = rsqrtf(d);
    dinv[i]  = di;
    dinv2[i] = di * di;
}

// ---------------------------------------------------------------------------
// Two-level exclusive scan of cnt[] -> row_ptr[]
// ---------------------------------------------------------------------------
__global__ __launch_bounds__(1024) void k_scan_blocks(const int* __restrict__ cnt,
                                                      int* __restrict__ row_ptr,
                                                      int* __restrict__ bsum) {
    __shared__ int s[1024];
    int gid = blockIdx.x * 1024 + threadIdx.x;
    int v = (gid < N) ? cnt[gid] : 0;
    s[threadIdx.x] = v;
    __syncthreads();
    for (int off = 1; off < 1024; off <<= 1) {
        int t = (threadIdx.x >= off) ? s[threadIdx.x - off] : 0;
        __syncthreads();
        s[threadIdx.x] += t;
        __syncthreads();
    }
    if (gid < N) row_ptr[gid] = s[threadIdx.x] - v;  // exclusive
    if (threadIdx.x == 1023) bsum[blockIdx.x] = s[1023];
}

__global__ void k_scan_sums(const int* __restrict__ bsum, int* __restrict__ boff, int nb) {
    int lane = threadIdx.x;  // single 64-lane wave
    int orig = (lane < nb) ? bsum[lane] : 0;
    int v = orig;
    for (int off = 1; off < 64; off <<= 1) {
        int t = __shfl_up(v, off, 64);
        if (lane >= off) v += t;
    }
    if (lane < nb) boff[lane] = v - orig;  // exclusive
}

__global__ __launch_bounds__(1024) void k_addoff(int* __restrict__ row_ptr,
                                                 const int* __restrict__ boff) {
    int gid = blockIdx.x * 1024 + threadIdx.x;
    if (gid < N) row_ptr[gid] += boff[blockIdx.x];
    if (gid == 0) row_ptr[N] = E;
}

// ---------------------------------------------------------------------------
// Scatter edges into CSR with precomputed normalized weight
// ---------------------------------------------------------------------------
__global__ void k_scatter(const int* __restrict__ row, const int* __restrict__ col,
                          const float* __restrict__ w, const float* __restrict__ dinv,
                          const int* __restrict__ row_ptr, int* __restrict__ fill,
                          int* __restrict__ ccol, float* __restrict__ cw) {
    int e = blockIdx.x * blockDim.x + threadIdx.x;
    if (e >= E) return;
    int r = row[e], c = col[e];
    int p = row_ptr[r] + atomicAdd(&fill[r], 1);
    ccol[p] = c;
    cw[p]   = dinv[r] * w[e] * dinv[c];
}

// ---------------------------------------------------------------------------
// One propagation hop: hout[i,:] = dinv2[i]*hin[i,:] + sum_j cw[j]*hin[ccol[j],:]
// acc += hout.  One wave per node, lane = feature (64 feats = 256B coalesced).
// ---------------------------------------------------------------------------
__global__ __launch_bounds__(256) void k_prop(const float* __restrict__ hin,
                                              float* __restrict__ hout,
                                              float* __restrict__ acc,
                                              const float* __restrict__ dinv2,
                                              const int* __restrict__ row_ptr,
                                              const int* __restrict__ ccol,
                                              const float* __restrict__ cw) {
    int node = blockIdx.x * 4 + (threadIdx.x >> 6);
    if (node >= N) return;
    int f = threadIdx.x & 63;
    float s = dinv2[node] * hin[node * H + f];
    int j = row_ptr[node], end = row_ptr[node + 1];
    for (; j < end; ++j) {
        s = fmaf(cw[j], hin[ccol[j] * H + f], s);
    }
    int idx = node * H + f;
    hout[idx] = s;
    acc[idx] += s;
}

// ---------------------------------------------------------------------------
// out = relu(CK*acc + AL*y0 + b1) @ W2 + b2
// Block = 256 threads handles 32 nodes; W2 + h-tile staged in LDS.
// ---------------------------------------------------------------------------
__global__ __launch_bounds__(256) void k_final(const float* __restrict__ y0,
                                               const float* __restrict__ acc,
                                               const float* __restrict__ b1,
                                               const float* __restrict__ W2,
                                               const float* __restrict__ b2,
                                               float* __restrict__ out) {
    __shared__ float w2s[H * C];   // 10 KB
    __shared__ float hs[32 * H];   // 8 KB
    __shared__ float b2s[C];
    for (int t = threadIdx.x; t < H * C; t += 256) w2s[t] = W2[t];
    if (threadIdx.x < C) b2s[threadIdx.x] = b2[threadIdx.x];
    int node0 = blockIdx.x * 32;
    for (int t = threadIdx.x; t < 32 * H; t += 256) {
        int nl = t >> 6, k = t & 63;
        int node = node0 + nl;
        float z = 0.0f;
        if (node < N) {
            int g = node * H + k;
            z = fmaxf(CK * acc[g] + AL * y0[g] + b1[k], 0.0f);
        }
        hs[t] = z;
    }
    __syncthreads();
    for (int o = threadIdx.x; o < 32 * C; o += 256) {
        int nl = o / C, c = o % C;
        int node = node0 + nl;
        if (node >= N) continue;
        float s = b2s[c];
        const float* hr = &hs[nl * H];
#pragma unroll
        for (int k = 0; k < H; ++k) s = fmaf(hr[k], w2s[k * C + c], s);
        out[node * C + c] = s;
    }
}

// ---------------------------------------------------------------------------
extern "C" void kernel_launch(void* const* d_in, const int* in_sizes, int n_in,
                              void* d_out, int out_size, void* d_ws, size_t ws_size,
                              hipStream_t stream) {
    const float* x  = (const float*)d_in[0];
    const int*   ei = (const int*)d_in[1];
    const float* ew = (const float*)d_in[2];
    const float* W1 = (const float*)d_in[3];
    const float* b1 = (const float*)d_in[4];
    const float* W2 = (const float*)d_in[5];
    const float* b2 = (const float*)d_in[6];
    float* out = (float*)d_out;

    const int* row = ei;        // edge_index[0]
    const int* col = ei + E;    // edge_index[1]

    // bump allocator over workspace (all offsets 1 KiB aligned)
    char* ws = (char*)d_ws;
    size_t off = 0;
    auto alloc = [&](size_t bytes) -> char* {
        char* p = ws + off;
        off = (off + bytes + 1023) & ~(size_t)1023;
        return p;
    };
    float* y0     = (float*)alloc((size_t)N * H * 4);
    float* ha     = (float*)alloc((size_t)N * H * 4);
    float* hb     = (float*)alloc((size_t)N * H * 4);
    float* acc    = (float*)alloc((size_t)N * H * 4);
    float* deg    = (float*)alloc((size_t)N * 4);      // zeroed
    int*   cnt    = (int*)  alloc((size_t)N * 4);      // zeroed
    int*   fill   = (int*)  alloc((size_t)N * 4);      // zeroed
    float* dinv   = (float*)alloc((size_t)N * 4);
    float* dinv2  = (float*)alloc((size_t)N * 4);
    int*   row_ptr= (int*)  alloc((size_t)(N + 1) * 4);
    int*   bsum   = (int*)  alloc(64 * 4);
    int*   boff   = (int*)  alloc(64 * 4);
    int*   ccol   = (int*)  alloc((size_t)E * 4);
    float* cw     = (float*)alloc((size_t)E * 4);

    // zero acc and the deg|cnt|fill span (contiguous in the bump order)
    hipMemsetAsync(acc, 0, (size_t)N * H * 4, stream);
    hipMemsetAsync(deg, 0, (size_t)((char*)dinv - (char*)deg), stream);

    // 1) y0 = x @ W1  (runs while preprocessing atomics proceed is fine: same stream, ordered)
    k_gemm1<<<(N + 3) / 4, 256, 0, stream>>>(x, W1, y0);

    // 2) degrees + counts
    k_degcount<<<(E + 255) / 256, 256, 0, stream>>>(row, ew, deg, cnt);
    k_dinv<<<(N + 255) / 256, 256, 0, stream>>>(deg, dinv, dinv2);

    // 3) scan counts -> row_ptr
    constexpr int NB = (N + 1023) / 1024;  // 49
    k_scan_blocks<<<NB, 1024, 0, stream>>>(cnt, row_ptr, bsum);
    k_scan_sums<<<1, 64, 0, stream>>>(bsum, boff, NB);
    k_addoff<<<NB, 1024, 0, stream>>>(row_ptr, boff);

    // 4) CSR scatter with normalized weights
    k_scatter<<<(E + 255) / 256, 256, 0, stream>>>(row, col, ew, dinv, row_ptr, fill, ccol, cw);

    // 5) K propagation hops (ping-pong), acc += each hop
    const float* hin = y0;
    float* bufs[2] = {ha, hb};
    for (int hop = 0; hop < K; ++hop) {
        float* hout = bufs[hop & 1];
        k_prop<<<(N + 3) / 4, 256, 0, stream>>>(hin, hout, acc, dinv2, row_ptr, ccol, cw);
        hin = hout;
    }

    // 6) fused epilogue MLP
    k_final<<<(N + 31) / 32, 256, 0, stream>>>(y0, acc, b1, W2, b2, out);
}

// Round 2
// 575.239 us; speedup vs baseline: 1.5360x; 1.5360x over previous
//
#include <hip/hip_runtime.h>
#include <math.h>

// Problem constants (fixed by the reference)
constexpr int   N   = 50000;
constexpr int   E   = 600000;
constexpr int   FIN = 128;
constexpr int   H   = 64;
constexpr int   C   = 40;
constexpr int   K   = 10;
constexpr float CK  = (1.0f - 0.1f) / 10.0f;  // (1-alpha)/K
constexpr float AL  = 0.1f;                   // alpha

// ---------------------------------------------------------------------------
// y0 = x @ W1   (N x 128) @ (128 x 64)
// 64 nodes per block: W1 staged in LDS ONCE, then 16 chunks of 4 nodes.
// ---------------------------------------------------------------------------
constexpr int G1_NODES = 64;
__global__ __launch_bounds__(256) void k_gemm1(const float* __restrict__ x,
                                               const float* __restrict__ W1,
                                               float* __restrict__ y0) {
    __shared__ float ws[FIN * H];   // 32 KB
    __shared__ float xs[4 * FIN];   // 2 KB
    for (int t = threadIdx.x; t < FIN * H; t += 256) ws[t] = W1[t];
    int nl = threadIdx.x >> 6;      // node-in-chunk 0..3
    int jj = threadIdx.x & 63;      // output column
    int base = blockIdx.x * G1_NODES;
    const float4* x4 = (const float4*)x;
    for (int chunk = 0; chunk < G1_NODES / 4; ++chunk) {
        int node0 = base + chunk * 4;
        __syncthreads();            // xs reads from previous chunk done (also covers ws stage)
        for (int t = threadIdx.x; t < 4 * (FIN / 4); t += 256) {   // 128 float4
            int nn = t >> 5;        // / (FIN/4)
            int kk = t & 31;
            int node = node0 + nn;
            ((float4*)xs)[t] = (node < N) ? x4[node * (FIN / 4) + kk]
                                          : make_float4(0.f, 0.f, 0.f, 0.f);
        }
        __syncthreads();
        int node = node0 + nl;
        if (node < N) {
            float s = 0.0f;
            const float* xr = &xs[nl * FIN];
#pragma unroll 8
            for (int k = 0; k < FIN; ++k) s = fmaf(xr[k], ws[k * H + jj], s);
            y0[node * H + jj] = s;
        }
    }
}

// ---------------------------------------------------------------------------
// Degree (weighted) + per-row edge count via atomics
// ---------------------------------------------------------------------------
__global__ void k_degcount(const int* __restrict__ row, const float* __restrict__ w,
                           float* __restrict__ deg, int* __restrict__ cnt) {
    int e = blockIdx.x * blockDim.x + threadIdx.x;
    if (e >= E) return;
    int r = row[e];
    atomicAdd(&deg[r], w[e]);
    atomicAdd(&cnt[r], 1);
}

__global__ void k_dinv(const float* __restrict__ deg, float* __restrict__ dinv,
                       float* __restrict__ dinv2) {
    int i = blockIdx.x * blockDim.x + threadIdx.x;
    if (i >= N) return;
    float d  = deg[i] + 1.0f;   // + self-loop weight
    float di = rsqrtf(d);
    dinv[i]  = di;
    dinv2[i] = di * di;
}

// ---------------------------------------------------------------------------
// Two-level exclusive scan of cnt[] -> row_ptr[]
// ---------------------------------------------------------------------------
__global__ __launch_bounds__(1024) void k_scan_blocks(const int* __restrict__ cnt,
                                                      int* __restrict__ row_ptr,
                                                      int* __restrict__ bsum) {
    __shared__ int s[1024];
    int gid = blockIdx.x * 1024 + threadIdx.x;
    int v = (gid < N) ? cnt[gid] : 0;
    s[threadIdx.x] = v;
    __syncthreads();
    for (int off = 1; off < 1024; off <<= 1) {
        int t = (threadIdx.x >= off) ? s[threadIdx.x - off] : 0;
        __syncthreads();
        s[threadIdx.x] += t;
        __syncthreads();
    }
    if (gid < N) row_ptr[gid] = s[threadIdx.x] - v;  // exclusive
    if (threadIdx.x == 1023) bsum[blockIdx.x] = s[1023];
}

__global__ void k_scan_sums(const int* __restrict__ bsum, int* __restrict__ boff, int nb) {
    int lane = threadIdx.x;  // single 64-lane wave
    int orig = (lane < nb) ? bsum[lane] : 0;
    int v = orig;
    for (int off = 1; off < 64; off <<= 1) {
        int t = __shfl_up(v, off, 64);
        if (lane >= off) v += t;
    }
    if (lane < nb) boff[lane] = v - orig;  // exclusive
}

__global__ __launch_bounds__(1024) void k_addoff(int* __restrict__ row_ptr,
                                                 const int* __restrict__ boff) {
    int gid = blockIdx.x * 1024 + threadIdx.x;
    if (gid < N) row_ptr[gid] += boff[blockIdx.x];
    if (gid == 0) row_ptr[N] = E;
}

// ---------------------------------------------------------------------------
// Scatter edges into CSR with precomputed normalized weight
// ---------------------------------------------------------------------------
__global__ void k_scatter(const int* __restrict__ row, const int* __restrict__ col,
                          const float* __restrict__ w, const float* __restrict__ dinv,
                          const int* __restrict__ row_ptr, int* __restrict__ fill,
                          int* __restrict__ ccol, float* __restrict__ cw) {
    int e = blockIdx.x * blockDim.x + threadIdx.x;
    if (e >= E) return;
    int r = row[e], c = col[e];
    int p = row_ptr[r] + atomicAdd(&fill[r], 1);
    ccol[p] = c;
    cw[p]   = dinv[r] * w[e] * dinv[c];
}

// ---------------------------------------------------------------------------
// One propagation hop, 4-edge-parallel gather:
//   wave = 1 node; 4 subgroups of 16 lanes; subgroup g handles edge j+g with
//   float4 per lane (16 lanes x 16B = 256B row). One dwordx4 instruction
//   gathers 4 edges -> 4x memory-level parallelism vs scalar-lane version.
//   Cross-group shfl reduction at the end; lanes 0-15 write float4.
// ---------------------------------------------------------------------------
template <bool WRITE_H, bool ACC_INIT>
__global__ __launch_bounds__(256) void k_prop(const float4* __restrict__ hin4,
                                              float4* __restrict__ hout4,
                                              float4* __restrict__ acc4,
                                              const float* __restrict__ dinv2,
                                              const int* __restrict__ row_ptr,
                                              const int* __restrict__ ccol,
                                              const float* __restrict__ cw) {
    int node = blockIdx.x * 4 + (threadIdx.x >> 6);
    if (node >= N) return;                 // wave-uniform
    int lane = threadIdx.x & 63;
    int g = lane >> 4;                     // edge subgroup 0..3
    int l = lane & 15;                     // feature quad (features 4l..4l+3)
    int start = row_ptr[node], end = row_ptr[node + 1];
    float4 s = make_float4(0.f, 0.f, 0.f, 0.f);
    for (int j = start; j < end; j += 4) {
        int je = j + g;
        int jc = (je < end) ? je : end - 1;     // clamp (loop entered => end>start)
        float w = (je < end) ? cw[jc] : 0.0f;
        int   c = ccol[jc];
        float4 v = hin4[c * (H / 4) + l];
        s.x = fmaf(w, v.x, s.x);
        s.y = fmaf(w, v.y, s.y);
        s.z = fmaf(w, v.z, s.z);
        s.w = fmaf(w, v.w, s.w);
    }
    // reduce subgroups: lanes l, l+16, l+32, l+48 -> lane l
    s.x += __shfl_down(s.x, 32, 64);
    s.y += __shfl_down(s.y, 32, 64);
    s.z += __shfl_down(s.z, 32, 64);
    s.w += __shfl_down(s.w, 32, 64);
    s.x += __shfl_down(s.x, 16, 64);
    s.y += __shfl_down(s.y, 16, 64);
    s.z += __shfl_down(s.z, 16, 64);
    s.w += __shfl_down(s.w, 16, 64);
    if (lane < 16) {
        int idx = node * (H / 4) + l;
        float  d2 = dinv2[node];
        float4 hn = hin4[idx];             // self-loop term
        s.x = fmaf(d2, hn.x, s.x);
        s.y = fmaf(d2, hn.y, s.y);
        s.z = fmaf(d2, hn.z, s.z);
        s.w = fmaf(d2, hn.w, s.w);
        if (WRITE_H) hout4[idx] = s;
        if (ACC_INIT) {
            acc4[idx] = s;
        } else {
            float4 a = acc4[idx];
            a.x += s.x; a.y += s.y; a.z += s.z; a.w += s.w;
            acc4[idx] = a;
        }
    }
}

// ---------------------------------------------------------------------------
// out = relu(CK*acc + AL*y0 + b1) @ W2 + b2
// ---------------------------------------------------------------------------
__global__ __launch_bounds__(256) void k_final(const float4* __restrict__ y04,
                                               const float4* __restrict__ acc4,
                                               const float* __restrict__ b1,
                                               const float* __restrict__ W2,
                                               const float* __restrict__ b2,
                                               float* __restrict__ out) {
    __shared__ float w2s[H * C];   // 10 KB
    __shared__ float hs[32 * H];   // 8 KB
    __shared__ float b2s[C];
    for (int t = threadIdx.x; t < H * C; t += 256) w2s[t] = W2[t];
    if (threadIdx.x < C) b2s[threadIdx.x] = b2[threadIdx.x];
    int node0 = blockIdx.x * 32;
    for (int t = threadIdx.x; t < 32 * (H / 4); t += 256) {   // 512 float4
        int nl = t >> 4;           // / (H/4)
        int kq = t & 15;           // feature quad
        int node = node0 + nl;
        float4 z = make_float4(0.f, 0.f, 0.f, 0.f);
        if (node < N) {
            int g = node * (H / 4) + kq;
            float4 a = acc4[g], y = y04[g];
            z.x = fmaxf(fmaf(CK, a.x, fmaf(AL, y.x, b1[kq * 4 + 0])), 0.f);
            z.y = fmaxf(fmaf(CK, a.y, fmaf(AL, y.y, b1[kq * 4 + 1])), 0.f);
            z.z = fmaxf(fmaf(CK, a.z, fmaf(AL, y.z, b1[kq * 4 + 2])), 0.f);
            z.w = fmaxf(fmaf(CK, a.w, fmaf(AL, y.w, b1[kq * 4 + 3])), 0.f);
        }
        ((float4*)hs)[t] = z;
    }
    __syncthreads();
    for (int o = threadIdx.x; o < 32 * C; o += 256) {
        int nl = o / C, c = o % C;
        int node = node0 + nl;
        if (node >= N) continue;
        float s = b2s[c];
        const float* hr = &hs[nl * H];
#pragma unroll
        for (int k = 0; k < H; ++k) s = fmaf(hr[k], w2s[k * C + c], s);
        out[node * C + c] = s;
    }
}

// ---------------------------------------------------------------------------
extern "C" void kernel_launch(void* const* d_in, const int* in_sizes, int n_in,
                              void* d_out, int out_size, void* d_ws, size_t ws_size,
                              hipStream_t stream) {
    const float* x  = (const float*)d_in[0];
    const int*   ei = (const int*)d_in[1];
    const float* ew = (const float*)d_in[2];
    const float* W1 = (const float*)d_in[3];
    const float* b1 = (const float*)d_in[4];
    const float* W2 = (const float*)d_in[5];
    const float* b2 = (const float*)d_in[6];
    float* out = (float*)d_out;

    const int* row = ei;        // edge_index[0]
    const int* col = ei + E;    // edge_index[1]

    // bump allocator over workspace (1 KiB aligned)
    char* ws = (char*)d_ws;
    size_t off = 0;
    auto alloc = [&](size_t bytes) -> char* {
        char* p = ws + off;
        off = (off + bytes + 1023) & ~(size_t)1023;
        return p;
    };
    float* y0     = (float*)alloc((size_t)N * H * 4);
    float* ha     = (float*)alloc((size_t)N * H * 4);
    float* hb     = (float*)alloc((size_t)N * H * 4);
    float* acc    = (float*)alloc((size_t)N * H * 4);
    float* deg    = (float*)alloc((size_t)N * 4);      // zeroed
    int*   cnt    = (int*)  alloc((size_t)N * 4);      // zeroed
    int*   fill   = (int*)  alloc((size_t)N * 4);      // zeroed
    float* dinv   = (float*)alloc((size_t)N * 4);
    float* dinv2  = (float*)alloc((size_t)N * 4);
    int*   row_ptr= (int*)  alloc((size_t)(N + 1) * 4);
    int*   bsum   = (int*)  alloc(64 * 4);
    int*   boff   = (int*)  alloc(64 * 4);
    int*   ccol   = (int*)  alloc((size_t)E * 4);
    float* cw     = (float*)alloc((size_t)E * 4);

    // zero the deg|cnt|fill span (contiguous in bump order); acc init'd by hop 0
    hipMemsetAsync(deg, 0, (size_t)((char*)dinv - (char*)deg), stream);

    // 1) y0 = x @ W1
    k_gemm1<<<(N + G1_NODES - 1) / G1_NODES, 256, 0, stream>>>(x, W1, y0);

    // 2) degrees + counts
    k_degcount<<<(E + 255) / 256, 256, 0, stream>>>(row, ew, deg, cnt);
    k_dinv<<<(N + 255) / 256, 256, 0, stream>>>(deg, dinv, dinv2);

    // 3) scan counts -> row_ptr
    constexpr int NB = (N + 1023) / 1024;  // 49
    k_scan_blocks<<<NB, 1024, 0, stream>>>(cnt, row_ptr, bsum);
    k_scan_sums<<<1, 64, 0, stream>>>(bsum, boff, NB);
    k_addoff<<<NB, 1024, 0, stream>>>(row_ptr, boff);

    // 4) CSR scatter with normalized weights
    k_scatter<<<(E + 255) / 256, 256, 0, stream>>>(row, col, ew, dinv, row_ptr, fill, ccol, cw);

    // 5) K propagation hops (ping-pong); hop 0 inits acc, last hop skips hout
    const float4* hin = (const float4*)y0;
    float4* bufs[2] = {(float4*)ha, (float4*)hb};
    float4* acc4 = (float4*)acc;
    int grid = (N + 3) / 4;
    for (int hop = 0; hop < K; ++hop) {
        float4* hout = bufs[hop & 1];
        if (hop == 0)
            k_prop<true, true><<<grid, 256, 0, stream>>>(hin, hout, acc4, dinv2, row_ptr, ccol, cw);
        else if (hop == K - 1)
            k_prop<false, false><<<grid, 256, 0, stream>>>(hin, hout, acc4, dinv2, row_ptr, ccol, cw);
        else
            k_prop<true, false><<<grid, 256, 0, stream>>>(hin, hout, acc4, dinv2, row_ptr, ccol, cw);
        hin = hout;
    }

    // 6) fused epilogue MLP
    k_final<<<(N + 31) / 32, 256, 0, stream>>>((const float4*)y0, acc4, b1, W2, b2, out);
}